// Round 7
// baseline (730.058 us; speedup 1.0000x reference)
//
#include <hip/hip_runtime.h>
#include <math.h>

#define NN 100000
#define EE 1600000
#define NBLK_SCAN 256
#define CHUNK ((NN + NBLK_SCAN - 1) / NBLK_SCAN)   // 391

typedef __attribute__((ext_vector_type(8))) short bf16x8;
typedef __attribute__((ext_vector_type(4))) float f32x4;

__device__ __forceinline__ ushort f2bf(float x) {
    uint u = __builtin_bit_cast(uint, x);
    u += 0x7fffu + ((u >> 16) & 1u);   // RNE
    return (ushort)(u >> 16);
}
__device__ __forceinline__ float bf2f(ushort u) {
    uint v = ((uint)u) << 16;
    return __builtin_bit_cast(float, v);
}

// ---------------- embed: h_emb = h @ emb_W + emb_b  (bf16 output) ----------------
__global__ __launch_bounds__(256) void embed_kernel(
    const float* __restrict__ h, const float* __restrict__ embW,
    const float* __restrict__ embB, ushort* __restrict__ hembb)
{
    int t = blockIdx.x * 256 + threadIdx.x;
    int n = t >> 6;
    int j = t & 63;
    if (n >= NN) return;
    float acc = embB[j];
#pragma unroll
    for (int k = 0; k < 16; ++k)
        acc = fmaf(h[n * 16 + k], embW[k * 64 + j], acc);
    hembb[n * 64 + j] = f2bf(acc);
}

// ---------------- sort: histogram ----------------
__global__ __launch_bounds__(256) void hist_kernel(
    const int* __restrict__ ei, int* __restrict__ hist)
{
    for (int e = blockIdx.x * 256 + threadIdx.x; e < EE; e += gridDim.x * 256)
        atomicAdd(&hist[ei[e]], 1);
}

// ---------------- sort: scan (3 kernels) ----------------
__global__ __launch_bounds__(256) void scan_a(const int* __restrict__ hist, int* __restrict__ bsum)
{
    __shared__ int red[256];
    const int b = blockIdx.x, t = threadIdx.x;
    const int start = b * CHUNK, end = min(NN, start + CHUNK);
    int s = 0;
    for (int i = start + t; i < end; i += 256) s += hist[i];
    red[t] = s; __syncthreads();
    for (int k = 128; k > 0; k >>= 1) { if (t < k) red[t] += red[t + k]; __syncthreads(); }
    if (t == 0) bsum[b] = red[0];
}

__global__ void scan_b(const int* __restrict__ bsum, int* __restrict__ boff)
{
    if (threadIdx.x == 0) {
        int acc = 0;
        for (int i = 0; i < NBLK_SCAN; ++i) { boff[i] = acc; acc += bsum[i]; }
    }
}

__global__ __launch_bounds__(256) void scan_c(
    const int* __restrict__ hist, const int* __restrict__ boff,
    int* __restrict__ csr, int* __restrict__ cursor)
{
    __shared__ int lds[CHUNK];
    const int b = blockIdx.x, t = threadIdx.x;
    const int start = b * CHUNK, end = min(NN, start + CHUNK), n = end - start;
    for (int i = t; i < n; i += 256) lds[i] = hist[start + i];
    __syncthreads();
    if (t == 0) {
        int acc = boff[b];
        for (int i = 0; i < n; ++i) { int v = lds[i]; lds[i] = acc; acc += v; }
        if (end == NN) csr[NN] = acc;   // == EE
    }
    __syncthreads();
    for (int i = t; i < n; i += 256) { csr[start + i] = lds[i]; cursor[start + i] = lds[i]; }
}

// ---------------- sort: scatter sorted (row,col) pairs ----------------
__global__ __launch_bounds__(256) void scatter_kernel(
    const int* __restrict__ ei, int* __restrict__ cursor, int2* __restrict__ srt)
{
    for (int e = blockIdx.x * 256 + threadIdx.x; e < EE; e += gridDim.x * 256) {
        const int row = ei[e];
        const int p = atomicAdd(&cursor[row], 1);
        srt[p] = make_int2(row, ei[EE + e]);
    }
}

// ---------------- edge kernel: MFMA edge MLP + w-MLP, run-flushed scatter ----------------
// 500 blocks x 8 waves; each wave owns 400 consecutive sorted positions (25 batches of 16).
// Round-7 changes vs round-6:
//   * ALL weight B-fragments live in LDS (block-shared, 32 KB, frag-ordered so a read is
//     one conflict-free ds_read_b128 at frag_base + lane*16B). Frees ~128 regs/wave.
//   * Layer-1 A-fragments load DIRECTLY from global hembb (no X staging, no gather regs):
//     lane (g,l15) reads hembb[row(l15)*64 + kc*32 + g*8] (16 B, row = one 128B line).
//   * __launch_bounds__(512,4): cap 128 VGPR -> 4 waves/SIMD; LDS 76 KB -> 2 blocks/CU.
// MFMA layout (mfma_f32_16x16x32_bf16):
//   A frag: lane l holds A[l&15][(l>>4)*8 + b]
//   B frag: lane l holds B[(l>>4)*8 + b][l&15]
//   D:      lane l, reg r holds D[(l>>4)*4 + r][l&15]
// Activation LDS is k-permuted: storage s holds column j(s) = (s>>2) + (s&3)*16.
__global__ __launch_bounds__(512, 4) void edge_kernel(
    const ushort* __restrict__ hembb, const float* __restrict__ x,
    const int2* __restrict__ srt,
    const float* __restrict__ eW1, const float* __restrict__ eb1,
    const float* __restrict__ eW2, const float* __restrict__ eb2,
    const float* __restrict__ wW1, const float* __restrict__ wb1,
    const float* __restrict__ wW2, const float* __restrict__ wb2,
    float* __restrict__ agg, float* __restrict__ vsum)
{
    // B-fragments: 32 frags x (64 lanes x 8 ush) = 16384 ush = 32 KB
    //   frags 0..15 : eW1  (kc*4+t)
    //   frags 16..23: eW2  (kc*4+t)
    //   frags 24..31: wW1  (kc*4+t)
    __shared__ ushort sWB[32 * 512];
    __shared__ ushort sS[8][2560];       // per-wave T1 [0..1280) / EF [1280..2560)
    __shared__ float  sScal[8][16][4];   // {rd, rd*cos2t, rd*sin2t, rd*phi}

    const int tid = threadIdx.x;
    const int wave = tid >> 6, lane = tid & 63;
    const int l15 = lane & 15, g = lane >> 4;

    // ---- one-time weight staging into LDS (split across waves) ----
#pragma unroll
    for (int q = 0; q < 2; ++q) {
        const int fi = wave * 2 + q;           // 0..15
        const int kc = fi >> 2, t = fi & 3;
        bf16x8 f;
#pragma unroll
        for (int b = 0; b < 8; ++b)
            f[b] = (short)f2bf(eW1[(kc * 32 + g * 8 + b) * 64 + t * 16 + l15]);
        *(bf16x8*)&sWB[fi * 512 + lane * 8] = f;
    }
    {
        const int kc = wave >> 2, t = wave & 3;
        bf16x8 f, fv;
#pragma unroll
        for (int b = 0; b < 8; ++b) {
            int s = kc * 32 + g * 8 + b;
            int j = (s >> 2) + (s & 3) * 16;   // permuted k
            f[b]  = (short)f2bf(eW2[j * 64 + t * 16 + l15]);
            fv[b] = (short)f2bf(wW1[j * 64 + t * 16 + l15]);
        }
        *(bf16x8*)&sWB[(16 + wave) * 512 + lane * 8] = f;
        *(bf16x8*)&sWB[(24 + wave) * 512 + lane * 8] = fv;
    }

    float b1v[4], b2v[4], wb1v[4], w2v[4], w128v[4];
#pragma unroll
    for (int t = 0; t < 4; ++t) {
        b1v[t]   = eb1[t * 16 + l15];
        b2v[t]   = eb2[t * 16 + l15];
        wb1v[t]  = wb1[t * 16 + l15];
        w2v[t]   = wW2[t * 16 + l15];
        w128v[t] = eW1[128 * 64 + t * 16 + l15];
    }
    const float wb2v = wb2[0];
    __syncthreads();   // weights visible to all waves; no barriers after this

    ushort* T1 = sS[wave];
    ushort* EF = sS[wave] + 1280;

    const int base = (blockIdx.x * 8 + wave) * 400;

    float carry = 0.f, carryv = 0.f;
    int cur_row = -1;

    for (int bt = 0; bt < 25; ++bt) {
        const int ebase = base + bt * 16;

        // ---- per-edge scalar prep on lanes 0..15 ----
        int rowv = 0, colv = 0;
        if (lane < 16) {
            const int2 rc = srt[ebase + lane];
            rowv = rc.x; colv = rc.y;
            const float dx = x[rowv * 3 + 0] - x[colv * 3 + 0];
            const float dy = x[rowv * 3 + 1] - x[colv * 3 + 1];
            const float dz = x[rowv * 3 + 2] - x[colv * 3 + 2];
            const float r2 = dx * dx + dy * dy;
            const float rdv = r2 + dz * dz;
            const float inv = (r2 > 0.f) ? (1.f / r2) : 0.f;
            const float c2  = (r2 > 0.f) ? ((dx * dx - dy * dy) * inv) : 1.f;
            const float sn2 = 2.f * dx * dy * inv;
            const float phi = atan2f(dz, sqrtf(r2));
            float4 sc = {rdv, rdv * c2, rdv * sn2, rdv * phi};
            *(float4*)&sScal[wave][lane][0] = sc;
        }

        // ---- layer-1 A-fragments: direct global loads (no staging) ----
        const int rowN = __shfl(rowv, l15);
        const int colN = __shfl(colv, l15);
        const bf16x8 a0 = *(const bf16x8*)&hembb[(size_t)rowN * 64 + g * 8];
        const bf16x8 a1 = *(const bf16x8*)&hembb[(size_t)rowN * 64 + 32 + g * 8];
        const bf16x8 a2 = *(const bf16x8*)&hembb[(size_t)colN * 64 + g * 8];
        const bf16x8 a3 = *(const bf16x8*)&hembb[(size_t)colN * 64 + 32 + g * 8];

        // ---- layer 1: acc = X(16x128) @ W1 + b1, + rank-1 rd * W1[128,:] ----
        f32x4 acc[4];
#pragma unroll
        for (int t = 0; t < 4; ++t) acc[t] = (f32x4){b1v[t], b1v[t], b1v[t], b1v[t]};
#pragma unroll
        for (int t = 0; t < 4; ++t) {
            acc[t] = __builtin_amdgcn_mfma_f32_16x16x32_bf16(
                a0, *(const bf16x8*)&sWB[(0 * 4 + t) * 512 + lane * 8], acc[t], 0, 0, 0);
            acc[t] = __builtin_amdgcn_mfma_f32_16x16x32_bf16(
                a1, *(const bf16x8*)&sWB[(1 * 4 + t) * 512 + lane * 8], acc[t], 0, 0, 0);
            acc[t] = __builtin_amdgcn_mfma_f32_16x16x32_bf16(
                a2, *(const bf16x8*)&sWB[(2 * 4 + t) * 512 + lane * 8], acc[t], 0, 0, 0);
            acc[t] = __builtin_amdgcn_mfma_f32_16x16x32_bf16(
                a3, *(const bf16x8*)&sWB[(3 * 4 + t) * 512 + lane * 8], acc[t], 0, 0, 0);
        }
#pragma unroll
        for (int r = 0; r < 4; ++r) {
            const float rd_r = sScal[wave][g * 4 + r][0];
#pragma unroll
            for (int t = 0; t < 4; ++t) acc[t][r] = fmaf(rd_r, w128v[t], acc[t][r]);
        }
        // relu + pack to T1 (permuted storage s = c*4 + t)
#pragma unroll
        for (int r = 0; r < 4; ++r) {
            const float v0 = fmaxf(acc[0][r], 0.f), v1 = fmaxf(acc[1][r], 0.f);
            const float v2 = fmaxf(acc[2][r], 0.f), v3 = fmaxf(acc[3][r], 0.f);
            uint2 p;
            p.x = (uint)f2bf(v0) | ((uint)f2bf(v1) << 16);
            p.y = (uint)f2bf(v2) | ((uint)f2bf(v3) << 16);
            *(uint2*)&T1[(g * 4 + r) * 80 + l15 * 4] = p;
        }

        // ---- layer 2: ef = t1(16x64) @ W2 + b2 (no relu) ----
        f32x4 acc2[4];
#pragma unroll
        for (int t = 0; t < 4; ++t) acc2[t] = (f32x4){b2v[t], b2v[t], b2v[t], b2v[t]};
#pragma unroll
        for (int kc = 0; kc < 2; ++kc) {
            bf16x8 a = *(const bf16x8*)&T1[l15 * 80 + kc * 32 + g * 8];
#pragma unroll
            for (int t = 0; t < 4; ++t)
                acc2[t] = __builtin_amdgcn_mfma_f32_16x16x32_bf16(
                    a, *(const bf16x8*)&sWB[(16 + kc * 4 + t) * 512 + lane * 8], acc2[t], 0, 0, 0);
        }
#pragma unroll
        for (int r = 0; r < 4; ++r) {
            uint2 p;
            p.x = (uint)f2bf(acc2[0][r]) | ((uint)f2bf(acc2[1][r]) << 16);
            p.y = (uint)f2bf(acc2[2][r]) | ((uint)f2bf(acc2[3][r]) << 16);
            *(uint2*)&EF[(g * 4 + r) * 80 + l15 * 4] = p;
        }

        // ---- w-MLP layer 1: s1 = ef @ wW1 + wb1 ----
        f32x4 acc3[4];
#pragma unroll
        for (int t = 0; t < 4; ++t) acc3[t] = (f32x4){wb1v[t], wb1v[t], wb1v[t], wb1v[t]};
#pragma unroll
        for (int kc = 0; kc < 2; ++kc) {
            bf16x8 a = *(const bf16x8*)&EF[l15 * 80 + kc * 32 + g * 8];
#pragma unroll
            for (int t = 0; t < 4; ++t)
                acc3[t] = __builtin_amdgcn_mfma_f32_16x16x32_bf16(
                    a, *(const bf16x8*)&sWB[(24 + kc * 4 + t) * 512 + lane * 8], acc3[t], 0, 0, 0);
        }
        // ---- w = relu(s1) . wW2 + wb2 : per-lane 4-col partial, reduce over 16 lanes ----
        float wfin[4];
#pragma unroll
        for (int r = 0; r < 4; ++r) {
            float p = fmaxf(acc3[0][r], 0.f) * w2v[0];
            p = fmaf(fmaxf(acc3[1][r], 0.f), w2v[1], p);
            p = fmaf(fmaxf(acc3[2][r], 0.f), w2v[2], p);
            p = fmaf(fmaxf(acc3[3][r], 0.f), w2v[3], p);
            wfin[r] = p;
        }
#pragma unroll
        for (int m = 1; m < 16; m <<= 1) {
#pragma unroll
            for (int r = 0; r < 4; ++r) wfin[r] += __shfl_xor(wfin[r], m);
        }
#pragma unroll
        for (int r = 0; r < 4; ++r) wfin[r] += wb2v;

        // ---- run-flush accumulation (rows sorted => long runs) ----
#pragma unroll
        for (int e = 0; e < 16; ++e) {
            const int row_e = __shfl(rowv, e);
            const float efv = bf2f(EF[e * 80 + l15 * 4 + g]);   // ef[e][lane]
            const float wE = __shfl(wfin[e & 3], (e >> 2) * 16);
            if (row_e != cur_row) {
                if (cur_row >= 0) {
                    unsafeAtomicAdd(&agg[(size_t)cur_row * 64 + lane], carry);
                    if (lane < 3) unsafeAtomicAdd(&vsum[cur_row * 4 + lane], carryv);
                }
                cur_row = row_e; carry = 0.f; carryv = 0.f;
            }
            carry += efv;
            if (lane < 3) carryv = fmaf(sScal[wave][e][1 + lane], wE, carryv);
        }
    }
    if (cur_row >= 0) {
        unsafeAtomicAdd(&agg[(size_t)cur_row * 64 + lane], carry);
        if (lane < 3) unsafeAtomicAdd(&vsum[cur_row * 4 + lane], carryv);
    }
}

// ---------------- node kernel: MFMA residual MLP + v normalize ----------------
// 4 waves/block, each wave owns one 16-node tile per iteration.
__global__ __launch_bounds__(256, 2) void node_kernel(
    const ushort* __restrict__ hembb, const float* __restrict__ agg,
    const float* __restrict__ nW1, const float* __restrict__ nb1,
    const float* __restrict__ nW2, const float* __restrict__ nb2,
    const float* __restrict__ vsum, const int* __restrict__ csr,
    float* __restrict__ outh, float* __restrict__ outv)
{
    __shared__ ushort sT1[4][16 * 80];

    const int tid = threadIdx.x;
    const int wave = tid >> 6, lane = tid & 63;
    const int l15 = lane & 15, g = lane >> 4;

    bf16x8 W1f[4][4], W2f[2][4];
#pragma unroll
    for (int kc = 0; kc < 4; ++kc)
#pragma unroll
        for (int t = 0; t < 4; ++t) {
            bf16x8 f;
#pragma unroll
            for (int b = 0; b < 8; ++b) {
                int k = kc * 32 + g * 8 + b;
                f[b] = (short)f2bf(nW1[k * 64 + t * 16 + l15]);
            }
            W1f[kc][t] = f;
        }
#pragma unroll
    for (int kc = 0; kc < 2; ++kc)
#pragma unroll
        for (int t = 0; t < 4; ++t) {
            bf16x8 f;
#pragma unroll
            for (int b = 0; b < 8; ++b) {
                int s = kc * 32 + g * 8 + b;
                int j = (s >> 2) + (s & 3) * 16;
                f[b] = (short)f2bf(nW2[j * 64 + t * 16 + l15]);
            }
            W2f[kc][t] = f;
        }
    float b1v[4], b2v[4];
#pragma unroll
    for (int t = 0; t < 4; ++t) { b1v[t] = nb1[t * 16 + l15]; b2v[t] = nb2[t * 16 + l15]; }

    ushort* T1 = sT1[wave];
    const int nwaves = gridDim.x * 4;
    const int ntiles = NN / 16;   // 6250

    for (int tile = blockIdx.x * 4 + wave; tile < ntiles; tile += nwaves) {
        const int nb = tile * 16;

        f32x4 acc[4];
#pragma unroll
        for (int t = 0; t < 4; ++t) acc[t] = (f32x4){b1v[t], b1v[t], b1v[t], b1v[t]};
        // h part (k 0..63): direct bf16x8 loads
#pragma unroll
        for (int kc = 0; kc < 2; ++kc) {
            bf16x8 a = *(const bf16x8*)&hembb[(size_t)(nb + l15) * 64 + kc * 32 + g * 8];
#pragma unroll
            for (int t = 0; t < 4; ++t)
                acc[t] = __builtin_amdgcn_mfma_f32_16x16x32_bf16(a, W1f[kc][t], acc[t], 0, 0, 0);
        }
        // agg part (k 64..127): f32 loads, convert
#pragma unroll
        for (int kc = 2; kc < 4; ++kc) {
            const float4 f0 = *(const float4*)&agg[(size_t)(nb + l15) * 64 + (kc - 2) * 32 + g * 8];
            const float4 f1 = *(const float4*)&agg[(size_t)(nb + l15) * 64 + (kc - 2) * 32 + g * 8 + 4];
            bf16x8 a;
            a[0] = (short)f2bf(f0.x); a[1] = (short)f2bf(f0.y);
            a[2] = (short)f2bf(f0.z); a[3] = (short)f2bf(f0.w);
            a[4] = (short)f2bf(f1.x); a[5] = (short)f2bf(f1.y);
            a[6] = (short)f2bf(f1.z); a[7] = (short)f2bf(f1.w);
#pragma unroll
            for (int t = 0; t < 4; ++t)
                acc[t] = __builtin_amdgcn_mfma_f32_16x16x32_bf16(a, W1f[kc][t], acc[t], 0, 0, 0);
        }
        // relu + pack permuted
#pragma unroll
        for (int r = 0; r < 4; ++r) {
            const float v0 = fmaxf(acc[0][r], 0.f), v1 = fmaxf(acc[1][r], 0.f);
            const float v2 = fmaxf(acc[2][r], 0.f), v3 = fmaxf(acc[3][r], 0.f);
            uint2 p;
            p.x = (uint)f2bf(v0) | ((uint)f2bf(v1) << 16);
            p.y = (uint)f2bf(v2) | ((uint)f2bf(v3) << 16);
            *(uint2*)&T1[(g * 4 + r) * 80 + l15 * 4] = p;
        }

        f32x4 acc2[4];
#pragma unroll
        for (int t = 0; t < 4; ++t) acc2[t] = (f32x4){b2v[t], b2v[t], b2v[t], b2v[t]};
#pragma unroll
        for (int kc = 0; kc < 2; ++kc) {
            bf16x8 a = *(const bf16x8*)&T1[l15 * 80 + kc * 32 + g * 8];
#pragma unroll
            for (int t = 0; t < 4; ++t)
                acc2[t] = __builtin_amdgcn_mfma_f32_16x16x32_bf16(a, W2f[kc][t], acc2[t], 0, 0, 0);
        }
        // residual + store
#pragma unroll
        for (int r = 0; r < 4; ++r) {
#pragma unroll
            for (int t = 0; t < 4; ++t) {
                const size_t idx = (size_t)(nb + g * 4 + r) * 64 + t * 16 + l15;
                outh[idx] = bf2f(hembb[idx]) + acc2[t][r];
            }
        }

        // v normalize: lanes 0..15, one node each
        if (g == 0) {
            const int n = nb + l15;
            const float c = fmaxf((float)(csr[n + 1] - csr[n]), 1.f);
            const float4 vs = *(const float4*)&vsum[n * 4];
            const float a0 = vs.x / c, a1 = vs.y / c, a2 = vs.z / c;
            const float nrm = fmaxf(sqrtf(a0 * a0 + a1 * a1 + a2 * a2), 1e-12f);
            outv[n * 3 + 0] = a0 / nrm;
            outv[n * 3 + 1] = a1 / nrm;
            outv[n * 3 + 2] = a2 / nrm;
        }
    }
}

extern "C" void kernel_launch(void* const* d_in, const int* in_sizes, int n_in,
                              void* d_out, int out_size, void* d_ws, size_t ws_size,
                              hipStream_t stream)
{
    const float* h    = (const float*)d_in[0];
    const float* x    = (const float*)d_in[1];
    const int*   ei   = (const int*)d_in[2];
    const float* embW = (const float*)d_in[3];
    const float* embB = (const float*)d_in[4];
    const float* eW1  = (const float*)d_in[5];
    const float* eb1  = (const float*)d_in[6];
    const float* eW2  = (const float*)d_in[7];
    const float* eb2  = (const float*)d_in[8];
    const float* nW1  = (const float*)d_in[9];
    const float* nb1  = (const float*)d_in[10];
    const float* nW2  = (const float*)d_in[11];
    const float* nb2  = (const float*)d_in[12];
    const float* wW1  = (const float*)d_in[13];
    const float* wb1  = (const float*)d_in[14];
    const float* wW2  = (const float*)d_in[15];
    const float* wb2  = (const float*)d_in[16];

    float* ws     = (float*)d_ws;
    ushort* hembb = (ushort*)ws;                        // N*64 bf16 (= N*32 floats)
    float* agg    = ws + (size_t)NN * 32;               // N*64
    float* vsum   = agg + (size_t)NN * 64;              // N*4
    int*   hist   = (int*)(vsum + (size_t)NN * 4);      // N
    int*   csr    = hist + NN;                          // N+1
    int*   cursor = csr + NN + 1;                       // N
    int*   bsum   = cursor + NN;                        // 256
    int*   boff   = bsum + NBLK_SCAN;                   // 256
    int2*  srt    = (int2*)(boff + NBLK_SCAN);          // E pairs

    float* outh = (float*)d_out;                        // N*64
    float* outx = outh + (size_t)NN * 64;               // N*3
    float* outv = outx + (size_t)NN * 3;                // N*3

    // zero agg, vsum, hist (contiguous)
    hipMemsetAsync(agg, 0, ((size_t)NN * 64 + NN * 4 + NN) * sizeof(float), stream);

    embed_kernel<<<NN * 64 / 256, 256, 0, stream>>>(h, embW, embB, hembb);
    hipMemcpyAsync(outx, x, (size_t)NN * 3 * sizeof(float), hipMemcpyDeviceToDevice, stream);

    hist_kernel<<<2048, 256, 0, stream>>>(ei, hist);
    scan_a<<<NBLK_SCAN, 256, 0, stream>>>(hist, bsum);
    scan_b<<<1, 64, 0, stream>>>(bsum, boff);
    scan_c<<<NBLK_SCAN, 256, 0, stream>>>(hist, boff, csr, cursor);
    scatter_kernel<<<2048, 256, 0, stream>>>(ei, cursor, srt);

    edge_kernel<<<500, 512, 0, stream>>>(hembb, x, srt, eW1, eb1, eW2, eb2,
                                         wW1, wb1, wW2, wb2, agg, vsum);
    node_kernel<<<1563, 256, 0, stream>>>(hembb, agg, nW1, nb1, nW2, nb2,
                                          vsum, csr, outh, outv);
}

// Round 8
// 474.510 us; speedup vs baseline: 1.5386x; 1.5386x over previous
//
#include <hip/hip_runtime.h>
#include <math.h>

#define NN 100000
#define EE 1600000
#define NBLK_SCAN 256
#define CHUNK ((NN + NBLK_SCAN - 1) / NBLK_SCAN)   // 391

typedef __attribute__((ext_vector_type(8))) short bf16x8;
typedef __attribute__((ext_vector_type(4))) float f32x4;

__device__ __forceinline__ ushort f2bf(float x) {
    uint u = __builtin_bit_cast(uint, x);
    u += 0x7fffu + ((u >> 16) & 1u);   // RNE
    return (ushort)(u >> 16);
}
__device__ __forceinline__ float bf2f(ushort u) {
    uint v = ((uint)u) << 16;
    return __builtin_bit_cast(float, v);
}

// ---------------- embed: h_emb = h @ emb_W + emb_b  (bf16 output) ----------------
__global__ __launch_bounds__(256) void embed_kernel(
    const float* __restrict__ h, const float* __restrict__ embW,
    const float* __restrict__ embB, ushort* __restrict__ hembb)
{
    int t = blockIdx.x * 256 + threadIdx.x;
    int n = t >> 6;
    int j = t & 63;
    if (n >= NN) return;
    float acc = embB[j];
#pragma unroll
    for (int k = 0; k < 16; ++k)
        acc = fmaf(h[n * 16 + k], embW[k * 64 + j], acc);
    hembb[n * 64 + j] = f2bf(acc);
}

// ---------------- sort: histogram ----------------
__global__ __launch_bounds__(256) void hist_kernel(
    const int* __restrict__ ei, int* __restrict__ hist)
{
    for (int e = blockIdx.x * 256 + threadIdx.x; e < EE; e += gridDim.x * 256)
        atomicAdd(&hist[ei[e]], 1);
}

// ---------------- sort: scan (3 kernels) ----------------
__global__ __launch_bounds__(256) void scan_a(const int* __restrict__ hist, int* __restrict__ bsum)
{
    __shared__ int red[256];
    const int b = blockIdx.x, t = threadIdx.x;
    const int start = b * CHUNK, end = min(NN, start + CHUNK);
    int s = 0;
    for (int i = start + t; i < end; i += 256) s += hist[i];
    red[t] = s; __syncthreads();
    for (int k = 128; k > 0; k >>= 1) { if (t < k) red[t] += red[t + k]; __syncthreads(); }
    if (t == 0) bsum[b] = red[0];
}

__global__ void scan_b(const int* __restrict__ bsum, int* __restrict__ boff)
{
    if (threadIdx.x == 0) {
        int acc = 0;
        for (int i = 0; i < NBLK_SCAN; ++i) { boff[i] = acc; acc += bsum[i]; }
    }
}

__global__ __launch_bounds__(256) void scan_c(
    const int* __restrict__ hist, const int* __restrict__ boff,
    int* __restrict__ csr, int* __restrict__ cursor)
{
    __shared__ int lds[CHUNK];
    const int b = blockIdx.x, t = threadIdx.x;
    const int start = b * CHUNK, end = min(NN, start + CHUNK), n = end - start;
    for (int i = t; i < n; i += 256) lds[i] = hist[start + i];
    __syncthreads();
    if (t == 0) {
        int acc = boff[b];
        for (int i = 0; i < n; ++i) { int v = lds[i]; lds[i] = acc; acc += v; }
        if (end == NN) csr[NN] = acc;   // == EE
    }
    __syncthreads();
    for (int i = t; i < n; i += 256) { csr[start + i] = lds[i]; cursor[start + i] = lds[i]; }
}

// ---------------- sort: scatter sorted (row,col) pairs ----------------
__global__ __launch_bounds__(256) void scatter_kernel(
    const int* __restrict__ ei, int* __restrict__ cursor, int2* __restrict__ srt)
{
    for (int e = blockIdx.x * 256 + threadIdx.x; e < EE; e += gridDim.x * 256) {
        const int row = ei[e];
        const int p = atomicAdd(&cursor[row], 1);
        srt[p] = make_int2(row, ei[EE + e]);
    }
}

// ---------------- edge kernel: MFMA edge MLP + w-MLP, run-flushed scatter ----------------
// 500 blocks x 8 waves; each wave owns 400 consecutive sorted positions (25 batches of 16).
// Structure (round-7) + launch bounds (round-6):
//   * Weight B-fragments in LDS (32 KB, frag-ordered, conflict-free ds_read_b128).
//   * Layer-1 A-fragments load directly from global hembb (no X staging).
//   * __launch_bounds__(512,2): on this hipcc the 2nd arg acts as workgroups/CU;
//     2 wg x 8 waves / 4 SIMD = 4 waves/SIMD -> 128-VGPR cap (spill-free, r6-verified).
//     (512,4) caps at 64 VGPR and SPILLS ~1.7 GB (r5/r7 regression) - do not use.
// MFMA layout (mfma_f32_16x16x32_bf16):
//   A frag: lane l holds A[l&15][(l>>4)*8 + b]
//   B frag: lane l holds B[(l>>4)*8 + b][l&15]
//   D:      lane l, reg r holds D[(l>>4)*4 + r][l&15]
// Activation LDS is k-permuted: storage s holds column j(s) = (s>>2) + (s&3)*16.
__global__ __launch_bounds__(512, 2) void edge_kernel(
    const ushort* __restrict__ hembb, const float* __restrict__ x,
    const int2* __restrict__ srt,
    const float* __restrict__ eW1, const float* __restrict__ eb1,
    const float* __restrict__ eW2, const float* __restrict__ eb2,
    const float* __restrict__ wW1, const float* __restrict__ wb1,
    const float* __restrict__ wW2, const float* __restrict__ wb2,
    float* __restrict__ agg, float* __restrict__ vsum)
{
    // B-fragments: 32 frags x (64 lanes x 8 ush) = 16384 ush = 32 KB
    //   frags 0..15 : eW1  (kc*4+t)
    //   frags 16..23: eW2  (kc*4+t)
    //   frags 24..31: wW1  (kc*4+t)
    __shared__ ushort sWB[32 * 512];
    __shared__ ushort sS[8][2560];       // per-wave T1 [0..1280) / EF [1280..2560)
    __shared__ float  sScal[8][16][4];   // {rd, rd*cos2t, rd*sin2t, rd*phi}

    const int tid = threadIdx.x;
    const int wave = tid >> 6, lane = tid & 63;
    const int l15 = lane & 15, g = lane >> 4;

    // ---- one-time weight staging into LDS (split across waves) ----
#pragma unroll
    for (int q = 0; q < 2; ++q) {
        const int fi = wave * 2 + q;           // 0..15
        const int kc = fi >> 2, t = fi & 3;
        bf16x8 f;
#pragma unroll
        for (int b = 0; b < 8; ++b)
            f[b] = (short)f2bf(eW1[(kc * 32 + g * 8 + b) * 64 + t * 16 + l15]);
        *(bf16x8*)&sWB[fi * 512 + lane * 8] = f;
    }
    {
        const int kc = wave >> 2, t = wave & 3;
        bf16x8 f, fv;
#pragma unroll
        for (int b = 0; b < 8; ++b) {
            int s = kc * 32 + g * 8 + b;
            int j = (s >> 2) + (s & 3) * 16;   // permuted k
            f[b]  = (short)f2bf(eW2[j * 64 + t * 16 + l15]);
            fv[b] = (short)f2bf(wW1[j * 64 + t * 16 + l15]);
        }
        *(bf16x8*)&sWB[(16 + wave) * 512 + lane * 8] = f;
        *(bf16x8*)&sWB[(24 + wave) * 512 + lane * 8] = fv;
    }

    float b1v[4], b2v[4], wb1v[4], w2v[4], w128v[4];
#pragma unroll
    for (int t = 0; t < 4; ++t) {
        b1v[t]   = eb1[t * 16 + l15];
        b2v[t]   = eb2[t * 16 + l15];
        wb1v[t]  = wb1[t * 16 + l15];
        w2v[t]   = wW2[t * 16 + l15];
        w128v[t] = eW1[128 * 64 + t * 16 + l15];
    }
    const float wb2v = wb2[0];
    __syncthreads();   // weights visible to all waves; no barriers after this

    ushort* T1 = sS[wave];
    ushort* EF = sS[wave] + 1280;

    const int base = (blockIdx.x * 8 + wave) * 400;

    float carry = 0.f, carryv = 0.f;
    int cur_row = -1;

    for (int bt = 0; bt < 25; ++bt) {
        const int ebase = base + bt * 16;

        // ---- per-edge scalar prep on lanes 0..15 ----
        int rowv = 0, colv = 0;
        if (lane < 16) {
            const int2 rc = srt[ebase + lane];
            rowv = rc.x; colv = rc.y;
            const float dx = x[rowv * 3 + 0] - x[colv * 3 + 0];
            const float dy = x[rowv * 3 + 1] - x[colv * 3 + 1];
            const float dz = x[rowv * 3 + 2] - x[colv * 3 + 2];
            const float r2 = dx * dx + dy * dy;
            const float rdv = r2 + dz * dz;
            const float inv = (r2 > 0.f) ? (1.f / r2) : 0.f;
            const float c2  = (r2 > 0.f) ? ((dx * dx - dy * dy) * inv) : 1.f;
            const float sn2 = 2.f * dx * dy * inv;
            const float phi = atan2f(dz, sqrtf(r2));
            float4 sc = {rdv, rdv * c2, rdv * sn2, rdv * phi};
            *(float4*)&sScal[wave][lane][0] = sc;
        }

        // ---- layer-1 A-fragments: direct global loads (no staging) ----
        const int rowN = __shfl(rowv, l15);
        const int colN = __shfl(colv, l15);
        const bf16x8 a0 = *(const bf16x8*)&hembb[(size_t)rowN * 64 + g * 8];
        const bf16x8 a1 = *(const bf16x8*)&hembb[(size_t)rowN * 64 + 32 + g * 8];
        const bf16x8 a2 = *(const bf16x8*)&hembb[(size_t)colN * 64 + g * 8];
        const bf16x8 a3 = *(const bf16x8*)&hembb[(size_t)colN * 64 + 32 + g * 8];

        // ---- layer 1: acc = X(16x128) @ W1 + b1, + rank-1 rd * W1[128,:] ----
        f32x4 acc[4];
#pragma unroll
        for (int t = 0; t < 4; ++t) acc[t] = (f32x4){b1v[t], b1v[t], b1v[t], b1v[t]};
#pragma unroll
        for (int t = 0; t < 4; ++t) {
            acc[t] = __builtin_amdgcn_mfma_f32_16x16x32_bf16(
                a0, *(const bf16x8*)&sWB[(0 * 4 + t) * 512 + lane * 8], acc[t], 0, 0, 0);
            acc[t] = __builtin_amdgcn_mfma_f32_16x16x32_bf16(
                a1, *(const bf16x8*)&sWB[(1 * 4 + t) * 512 + lane * 8], acc[t], 0, 0, 0);
            acc[t] = __builtin_amdgcn_mfma_f32_16x16x32_bf16(
                a2, *(const bf16x8*)&sWB[(2 * 4 + t) * 512 + lane * 8], acc[t], 0, 0, 0);
            acc[t] = __builtin_amdgcn_mfma_f32_16x16x32_bf16(
                a3, *(const bf16x8*)&sWB[(3 * 4 + t) * 512 + lane * 8], acc[t], 0, 0, 0);
        }
#pragma unroll
        for (int r = 0; r < 4; ++r) {
            const float rd_r = sScal[wave][g * 4 + r][0];
#pragma unroll
            for (int t = 0; t < 4; ++t) acc[t][r] = fmaf(rd_r, w128v[t], acc[t][r]);
        }
        // relu + pack to T1 (permuted storage s = c*4 + t)
#pragma unroll
        for (int r = 0; r < 4; ++r) {
            const float v0 = fmaxf(acc[0][r], 0.f), v1 = fmaxf(acc[1][r], 0.f);
            const float v2 = fmaxf(acc[2][r], 0.f), v3 = fmaxf(acc[3][r], 0.f);
            uint2 p;
            p.x = (uint)f2bf(v0) | ((uint)f2bf(v1) << 16);
            p.y = (uint)f2bf(v2) | ((uint)f2bf(v3) << 16);
            *(uint2*)&T1[(g * 4 + r) * 80 + l15 * 4] = p;
        }

        // ---- layer 2: ef = t1(16x64) @ W2 + b2 (no relu) ----
        f32x4 acc2[4];
#pragma unroll
        for (int t = 0; t < 4; ++t) acc2[t] = (f32x4){b2v[t], b2v[t], b2v[t], b2v[t]};
#pragma unroll
        for (int kc = 0; kc < 2; ++kc) {
            bf16x8 a = *(const bf16x8*)&T1[l15 * 80 + kc * 32 + g * 8];
#pragma unroll
            for (int t = 0; t < 4; ++t)
                acc2[t] = __builtin_amdgcn_mfma_f32_16x16x32_bf16(
                    a, *(const bf16x8*)&sWB[(16 + kc * 4 + t) * 512 + lane * 8], acc2[t], 0, 0, 0);
        }
#pragma unroll
        for (int r = 0; r < 4; ++r) {
            uint2 p;
            p.x = (uint)f2bf(acc2[0][r]) | ((uint)f2bf(acc2[1][r]) << 16);
            p.y = (uint)f2bf(acc2[2][r]) | ((uint)f2bf(acc2[3][r]) << 16);
            *(uint2*)&EF[(g * 4 + r) * 80 + l15 * 4] = p;
        }

        // ---- w-MLP layer 1: s1 = ef @ wW1 + wb1 ----
        f32x4 acc3[4];
#pragma unroll
        for (int t = 0; t < 4; ++t) acc3[t] = (f32x4){wb1v[t], wb1v[t], wb1v[t], wb1v[t]};
#pragma unroll
        for (int kc = 0; kc < 2; ++kc) {
            bf16x8 a = *(const bf16x8*)&EF[l15 * 80 + kc * 32 + g * 8];
#pragma unroll
            for (int t = 0; t < 4; ++t)
                acc3[t] = __builtin_amdgcn_mfma_f32_16x16x32_bf16(
                    a, *(const bf16x8*)&sWB[(24 + kc * 4 + t) * 512 + lane * 8], acc3[t], 0, 0, 0);
        }
        // ---- w = relu(s1) . wW2 + wb2 : per-lane 4-col partial, reduce over 16 lanes ----
        float wfin[4];
#pragma unroll
        for (int r = 0; r < 4; ++r) {
            float p = fmaxf(acc3[0][r], 0.f) * w2v[0];
            p = fmaf(fmaxf(acc3[1][r], 0.f), w2v[1], p);
            p = fmaf(fmaxf(acc3[2][r], 0.f), w2v[2], p);
            p = fmaf(fmaxf(acc3[3][r], 0.f), w2v[3], p);
            wfin[r] = p;
        }
#pragma unroll
        for (int m = 1; m < 16; m <<= 1) {
#pragma unroll
            for (int r = 0; r < 4; ++r) wfin[r] += __shfl_xor(wfin[r], m);
        }
#pragma unroll
        for (int r = 0; r < 4; ++r) wfin[r] += wb2v;

        // ---- run-flush accumulation (rows sorted => long runs) ----
#pragma unroll
        for (int e = 0; e < 16; ++e) {
            const int row_e = __shfl(rowv, e);
            const float efv = bf2f(EF[e * 80 + l15 * 4 + g]);   // ef[e][lane]
            const float wE = __shfl(wfin[e & 3], (e >> 2) * 16);
            if (row_e != cur_row) {
                if (cur_row >= 0) {
                    unsafeAtomicAdd(&agg[(size_t)cur_row * 64 + lane], carry);
                    if (lane < 3) unsafeAtomicAdd(&vsum[cur_row * 4 + lane], carryv);
                }
                cur_row = row_e; carry = 0.f; carryv = 0.f;
            }
            carry += efv;
            if (lane < 3) carryv = fmaf(sScal[wave][e][1 + lane], wE, carryv);
        }
    }
    if (cur_row >= 0) {
        unsafeAtomicAdd(&agg[(size_t)cur_row * 64 + lane], carry);
        if (lane < 3) unsafeAtomicAdd(&vsum[cur_row * 4 + lane], carryv);
    }
}

// ---------------- node kernel: MFMA residual MLP + v normalize ----------------
// 4 waves/block, each wave owns one 16-node tile per iteration.
__global__ __launch_bounds__(256, 2) void node_kernel(
    const ushort* __restrict__ hembb, const float* __restrict__ agg,
    const float* __restrict__ nW1, const float* __restrict__ nb1,
    const float* __restrict__ nW2, const float* __restrict__ nb2,
    const float* __restrict__ vsum, const int* __restrict__ csr,
    float* __restrict__ outh, float* __restrict__ outv)
{
    __shared__ ushort sT1[4][16 * 80];

    const int tid = threadIdx.x;
    const int wave = tid >> 6, lane = tid & 63;
    const int l15 = lane & 15, g = lane >> 4;

    bf16x8 W1f[4][4], W2f[2][4];
#pragma unroll
    for (int kc = 0; kc < 4; ++kc)
#pragma unroll
        for (int t = 0; t < 4; ++t) {
            bf16x8 f;
#pragma unroll
            for (int b = 0; b < 8; ++b) {
                int k = kc * 32 + g * 8 + b;
                f[b] = (short)f2bf(nW1[k * 64 + t * 16 + l15]);
            }
            W1f[kc][t] = f;
        }
#pragma unroll
    for (int kc = 0; kc < 2; ++kc)
#pragma unroll
        for (int t = 0; t < 4; ++t) {
            bf16x8 f;
#pragma unroll
            for (int b = 0; b < 8; ++b) {
                int s = kc * 32 + g * 8 + b;
                int j = (s >> 2) + (s & 3) * 16;
                f[b] = (short)f2bf(nW2[j * 64 + t * 16 + l15]);
            }
            W2f[kc][t] = f;
        }
    float b1v[4], b2v[4];
#pragma unroll
    for (int t = 0; t < 4; ++t) { b1v[t] = nb1[t * 16 + l15]; b2v[t] = nb2[t * 16 + l15]; }

    ushort* T1 = sT1[wave];
    const int nwaves = gridDim.x * 4;
    const int ntiles = NN / 16;   // 6250

    for (int tile = blockIdx.x * 4 + wave; tile < ntiles; tile += nwaves) {
        const int nb = tile * 16;

        f32x4 acc[4];
#pragma unroll
        for (int t = 0; t < 4; ++t) acc[t] = (f32x4){b1v[t], b1v[t], b1v[t], b1v[t]};
        // h part (k 0..63): direct bf16x8 loads
#pragma unroll
        for (int kc = 0; kc < 2; ++kc) {
            bf16x8 a = *(const bf16x8*)&hembb[(size_t)(nb + l15) * 64 + kc * 32 + g * 8];
#pragma unroll
            for (int t = 0; t < 4; ++t)
                acc[t] = __builtin_amdgcn_mfma_f32_16x16x32_bf16(a, W1f[kc][t], acc[t], 0, 0, 0);
        }
        // agg part (k 64..127): f32 loads, convert
#pragma unroll
        for (int kc = 2; kc < 4; ++kc) {
            const float4 f0 = *(const float4*)&agg[(size_t)(nb + l15) * 64 + (kc - 2) * 32 + g * 8];
            const float4 f1 = *(const float4*)&agg[(size_t)(nb + l15) * 64 + (kc - 2) * 32 + g * 8 + 4];
            bf16x8 a;
            a[0] = (short)f2bf(f0.x); a[1] = (short)f2bf(f0.y);
            a[2] = (short)f2bf(f0.z); a[3] = (short)f2bf(f0.w);
            a[4] = (short)f2bf(f1.x); a[5] = (short)f2bf(f1.y);
            a[6] = (short)f2bf(f1.z); a[7] = (short)f2bf(f1.w);
#pragma unroll
            for (int t = 0; t < 4; ++t)
                acc[t] = __builtin_amdgcn_mfma_f32_16x16x32_bf16(a, W1f[kc][t], acc[t], 0, 0, 0);
        }
        // relu + pack permuted
#pragma unroll
        for (int r = 0; r < 4; ++r) {
            const float v0 = fmaxf(acc[0][r], 0.f), v1 = fmaxf(acc[1][r], 0.f);
            const float v2 = fmaxf(acc[2][r], 0.f), v3 = fmaxf(acc[3][r], 0.f);
            uint2 p;
            p.x = (uint)f2bf(v0) | ((uint)f2bf(v1) << 16);
            p.y = (uint)f2bf(v2) | ((uint)f2bf(v3) << 16);
            *(uint2*)&T1[(g * 4 + r) * 80 + l15 * 4] = p;
        }

        f32x4 acc2[4];
#pragma unroll
        for (int t = 0; t < 4; ++t) acc2[t] = (f32x4){b2v[t], b2v[t], b2v[t], b2v[t]};
#pragma unroll
        for (int kc = 0; kc < 2; ++kc) {
            bf16x8 a = *(const bf16x8*)&T1[l15 * 80 + kc * 32 + g * 8];
#pragma unroll
            for (int t = 0; t < 4; ++t)
                acc2[t] = __builtin_amdgcn_mfma_f32_16x16x32_bf16(a, W2f[kc][t], acc2[t], 0, 0, 0);
        }
        // residual + store
#pragma unroll
        for (int r = 0; r < 4; ++r) {
#pragma unroll
            for (int t = 0; t < 4; ++t) {
                const size_t idx = (size_t)(nb + g * 4 + r) * 64 + t * 16 + l15;
                outh[idx] = bf2f(hembb[idx]) + acc2[t][r];
            }
        }

        // v normalize: lanes 0..15, one node each
        if (g == 0) {
            const int n = nb + l15;
            const float c = fmaxf((float)(csr[n + 1] - csr[n]), 1.f);
            const float4 vs = *(const float4*)&vsum[n * 4];
            const float a0 = vs.x / c, a1 = vs.y / c, a2 = vs.z / c;
            const float nrm = fmaxf(sqrtf(a0 * a0 + a1 * a1 + a2 * a2), 1e-12f);
            outv[n * 3 + 0] = a0 / nrm;
            outv[n * 3 + 1] = a1 / nrm;
            outv[n * 3 + 2] = a2 / nrm;
        }
    }
}

extern "C" void kernel_launch(void* const* d_in, const int* in_sizes, int n_in,
                              void* d_out, int out_size, void* d_ws, size_t ws_size,
                              hipStream_t stream)
{
    const float* h    = (const float*)d_in[0];
    const float* x    = (const float*)d_in[1];
    const int*   ei   = (const int*)d_in[2];
    const float* embW = (const float*)d_in[3];
    const float* embB = (const float*)d_in[4];
    const float* eW1  = (const float*)d_in[5];
    const float* eb1  = (const float*)d_in[6];
    const float* eW2  = (const float*)d_in[7];
    const float* eb2  = (const float*)d_in[8];
    const float* nW1  = (const float*)d_in[9];
    const float* nb1  = (const float*)d_in[10];
    const float* nW2  = (const float*)d_in[11];
    const float* nb2  = (const float*)d_in[12];
    const float* wW1  = (const float*)d_in[13];
    const float* wb1  = (const float*)d_in[14];
    const float* wW2  = (const float*)d_in[15];
    const float* wb2  = (const float*)d_in[16];

    float* ws     = (float*)d_ws;
    ushort* hembb = (ushort*)ws;                        // N*64 bf16 (= N*32 floats)
    float* agg    = ws + (size_t)NN * 32;               // N*64
    float* vsum   = agg + (size_t)NN * 64;              // N*4
    int*   hist   = (int*)(vsum + (size_t)NN * 4);      // N
    int*   csr    = hist + NN;                          // N+1
    int*   cursor = csr + NN + 1;                       // N
    int*   bsum   = cursor + NN;                        // 256
    int*   boff   = bsum + NBLK_SCAN;                   // 256
    int2*  srt    = (int2*)(boff + NBLK_SCAN);          // E pairs

    float* outh = (float*)d_out;                        // N*64
    float* outx = outh + (size_t)NN * 64;               // N*3
    float* outv = outx + (size_t)NN * 3;                // N*3

    // zero agg, vsum, hist (contiguous)
    hipMemsetAsync(agg, 0, ((size_t)NN * 64 + NN * 4 + NN) * sizeof(float), stream);

    embed_kernel<<<NN * 64 / 256, 256, 0, stream>>>(h, embW, embB, hembb);
    hipMemcpyAsync(outx, x, (size_t)NN * 3 * sizeof(float), hipMemcpyDeviceToDevice, stream);

    hist_kernel<<<2048, 256, 0, stream>>>(ei, hist);
    scan_a<<<NBLK_SCAN, 256, 0, stream>>>(hist, bsum);
    scan_b<<<1, 64, 0, stream>>>(bsum, boff);
    scan_c<<<NBLK_SCAN, 256, 0, stream>>>(hist, boff, csr, cursor);
    scatter_kernel<<<2048, 256, 0, stream>>>(ei, cursor, srt);

    edge_kernel<<<500, 512, 0, stream>>>(hembb, x, srt, eW1, eb1, eW2, eb2,
                                         wW1, wb1, wW2, wb2, agg, vsum);
    node_kernel<<<1563, 256, 0, stream>>>(hembb, agg, nW1, nb1, nW2, nb2,
                                          vsum, csr, outh, outv);
}